// Round 9
// baseline (323.165 us; speedup 1.0000x reference)
//
#include <hip/hip_runtime.h>

#define CH 30
#define CELLS 49
#define ROW 1470           // floats per batch row
#define NPAIR 735u         // float2 pairs per row
#define RPB 4              // rows per row-role block (one per wave)
#define THREADS 256

__device__ __forceinline__ float waveReduce(float v) {
    #pragma unroll
    for (int o = 32; o > 0; o >>= 1) v += __shfl_xor(v, o, 64);
    return v;
}

// Single fused kernel, role-split grid:
//   blocks [0, NSb)        : linear grid-stride stream -> cls + noobj losses
//   blocks [NSb, NBLK)     : per-wave row box/IoU work -> coord + obj losses
// Deterministic per-block partials in ws; last-arriving block finalizes.
__global__ __launch_bounds__(256, 4) void yolo_fused(const float* __restrict__ pred,
                                                     const float* __restrict__ targ,
                                                     float* __restrict__ ws,
                                                     int* __restrict__ cnt,
                                                     float* __restrict__ out,
                                                     int B, int NSb, int NBLK,
                                                     unsigned total, float invB) {
    const int w = threadIdx.x >> 6;
    const int lane = threadIdx.x & 63;

    __shared__ float4 boxS[RPB][2 * CELLS];   // wave-private slices
    __shared__ int clist[RPB][CELLS];
    __shared__ float sred[RPB][3];
    __shared__ int lastFlag;

    float cls = 0.f, objc = 0.f, coord = 0.f;

    if ((int)blockIdx.x < NSb) {
        // ================= stream role: fillBuffer-style linear read =========
        const float2* p2 = (const float2*)pred;
        const float2* t2 = (const float2*)targ;
        const unsigned stride = (unsigned)NSb * THREADS;
        for (unsigned g = blockIdx.x * THREADS + threadIdx.x; g < total; g += stride) {
            const float2 p = p2[g];                 // purely sequential across grid
            const float2 t = t2[g];
            const unsigned r = g / NPAIR;           // magic-mul
            const unsigned j = g - r * NPAIR;
            const unsigned cell = j / 15u;
            const unsigned ch0 = 2u * (j - cell * 15u);
            // conf of this pair's cell: same/nearby cache line as the stream -> L1-hot
            const float conf = targ[(size_t)r * ROW + cell * CH + 4];
            const float wobj = conf > 0.f ? 1.f : 0.f;
            const float dx = p.x - t.x;
            const float dy = p.y - t.y;
            // class loss (channels 10..29, obj cells)
            cls += (ch0 >= 10u) ? wobj * (dx * dx + dy * dy) : 0.f;
            // noobj conf loss x0.5 folded (ch4 = .x of pair rem2, ch9 = .y of rem4)
            const float nn = (ch0 == 4u ? dx * dx : 0.f) + (ch0 == 8u ? dy * dy : 0.f);
            objc += 0.5f * (1.f - wobj) * nn;
        }
    } else {
        // ================= row role: box/IoU losses (wave per row) ===========
        const int r = ((int)blockIdx.x - NSb) * RPB + w;
        if (r < B) {                                // wave-uniform; no barriers inside
            const float* P = pred + (size_t)r * ROW;
            const float* T = targ + (size_t)r * ROW;

            const bool isObj = (lane < CELLS) && (T[lane * CH + 4] > 0.f);
            const unsigned long long mask = __ballot(isObj);
            const int nObj = __popcll(mask);
            if (isObj) clist[w][__popcll(mask & ((1ull << lane) - 1ull))] = lane;
            const int nBox = 2 * nObj;

            // masked pred boxes -> xyxy in wave-private LDS
            for (int e = lane; e < nBox; e += 64) {
                const int c = clist[w][e >> 1];
                const float* pb = P + c * CH + (e & 1) * 5;
                const float cx = pb[0], cy = pb[1], bw = pb[2], bh = pb[3];
                boxS[w][e] = make_float4(cx - 0.5f * bw, cy - 0.5f * bh,
                                         cx + 0.5f * bw, cy + 0.5f * bh);
            }

            // per masked target box: max IoU over masked pred boxes; losses
            for (int e = lane; e < nBox; e += 64) {
                const int c = clist[w][e >> 1];
                const float* tb = T + c * CH + (e & 1) * 5;
                const float* pb = P + c * CH + (e & 1) * 5;
                const float tcx = tb[0], tcy = tb[1], tw = tb[2], th = tb[3];
                const float tx1 = tcx - 0.5f * tw, ty1 = tcy - 0.5f * th;
                const float tx2 = tcx + 0.5f * tw, ty2 = tcy + 0.5f * th;
                const float ta = (tx2 - tx1) * (ty2 - ty1);
                float maxiou = 0.f;
                for (int i = 0; i < nBox; ++i) {
                    const float4 b4 = boxS[w][i];   // wave-uniform = broadcast
                    const float lx = fmaxf(b4.x, tx1), ly = fmaxf(b4.y, ty1);
                    const float rx = fminf(b4.z, tx2), ry = fminf(b4.w, ty2);
                    const float iw = fmaxf(rx - lx, 0.f), ih = fmaxf(ry - ly, 0.f);
                    const float inter = iw * ih;
                    const float pa = (b4.z - b4.x) * (b4.w - b4.y);
                    const float un = pa + ta - inter;
                    const float iou = inter / (un > 0.f ? un : 1.f);
                    maxiou = fmaxf(maxiou, iou);
                }
                if (maxiou != 0.f) {                // cmask
                    const float dcx = pb[0] - tcx, dcy = pb[1] - tcy;
                    coord += dcx * dcx + dcy * dcy;
                    const float dw = sqrtf(pb[2]) - sqrtf(tw);
                    const float dh = sqrtf(pb[3]) - sqrtf(th);
                    coord += dw * dw + dh * dh;
                    const float dc = pb[4] - tb[4];
                    objc += dc * dc;
                }
            }
        }
    }

    // ---- wave reduce -> block triple -> arrival counter ----
    cls = waveReduce(cls); objc = waveReduce(objc); coord = waveReduce(coord);
    if (lane == 0) { sred[w][0] = cls; sred[w][1] = objc; sred[w][2] = coord; }
    __syncthreads();
    if (threadIdx.x == 0) {
        float c = 0.f, o = 0.f, x = 0.f;
        #pragma unroll
        for (int i = 0; i < RPB; ++i) { c += sred[i][0]; o += sred[i][1]; x += sred[i][2]; }
        ws[blockIdx.x] = c;
        ws[NBLK + blockIdx.x] = o;
        ws[2 * NBLK + blockIdx.x] = x;
        __threadfence();                            // release block triple
        const int old = atomicAdd(cnt, 1);
        lastFlag = (old == NBLK - 1) ? 1 : 0;
    }
    __syncthreads();

    // ---- last block finalizes (deterministic accumulation order) ----
    if (lastFlag) {
        __threadfence();                            // acquire other blocks' triples
        float c = 0.f, o = 0.f, x = 0.f;
        for (int i = threadIdx.x; i < NBLK; i += THREADS) {
            c += ws[i];
            o += ws[NBLK + i];
            x += ws[2 * NBLK + i];
        }
        c = waveReduce(c); o = waveReduce(o); x = waveReduce(x);
        if (lane == 0) { sred[w][0] = c; sred[w][1] = o; sred[w][2] = x; }
        __syncthreads();
        if (threadIdx.x == 0) {
            float C = 0.f, O = 0.f, X = 0.f;
            #pragma unroll
            for (int i = 0; i < RPB; ++i) { C += sred[i][0]; O += sred[i][1]; X += sred[i][2]; }
            const float bcls = C * invB;
            const float bobj = O * invB;            // noobj*0.5 folded upstream
            const float bcoord = X * 5.0f * invB;   // COORD_LAMBDA
            out[0] = bcls + bobj + bcoord;
            out[1] = bcls;
            out[2] = bobj;
            out[3] = bcoord;
        }
    }
}

extern "C" void kernel_launch(void* const* d_in, const int* in_sizes, int n_in,
                              void* d_out, int out_size, void* d_ws, size_t ws_size,
                              hipStream_t stream) {
    const float* pred = (const float*)d_in[0];
    const float* targ = (const float*)d_in[1];
    float* ws = (float*)d_ws;
    float* out = (float*)d_out;
    const int B = in_sizes[0] / ROW;
    const int NR = (B + RPB - 1) / RPB;             // row-role blocks
    const int NS = 2 * NR;                          // stream-role blocks
    const int NBLK = NS + NR;
    const unsigned total = (unsigned)B * NPAIR;     // float2 pairs overall
    int* cnt = (int*)(ws + 3 * NBLK);

    hipMemsetAsync(cnt, 0, sizeof(int), stream);    // zero arrival counter
    yolo_fused<<<NBLK, THREADS, 0, stream>>>(pred, targ, ws, cnt, out,
                                             B, NS, NBLK, total, 1.0f / (float)B);
}

// Round 10
// 135.456 us; speedup vs baseline: 2.3858x; 2.3858x over previous
//
#include <hip/hip_runtime.h>

#define CH 30
#define CELLS 49
#define ROW 1470            // floats per batch row
#define NF4 735             // float4s per 2-row region (11760 B, 16B-aligned)
#define SLOTS 12            // float4 slots per lane (12*64 = 768 >= 735)
#define DEPTH 6             // pipeline depth: slots in flight
#define THREADS 128         // 2 waves per block, 2 rows per wave

__device__ __forceinline__ float waveReduce(float v) {
    #pragma unroll
    for (int o = 32; o > 0; o >>= 1) v += __shfl_xor(v, o, 64);
    return v;
}

// Per-wave box/IoU losses for one row (reads global directly; cache-warm).
// boxS/clist are wave-private LDS slices; no barriers (wave lockstep).
__device__ __forceinline__ void boxRow(const float* __restrict__ P,
                                       const float* __restrict__ T,
                                       unsigned long long mask, int lane,
                                       float4* boxS, int* clist,
                                       float& objc, float& coord) {
    const int nObj = __popcll(mask);
    const bool isObj = (lane < CELLS) && ((mask >> lane) & 1ull);
    if (isObj) clist[__popcll(mask & ((1ull << lane) - 1ull))] = lane;
    const int nBox = 2 * nObj;

    for (int e = lane; e < nBox; e += 64) {
        const int c = clist[e >> 1];
        const float* pb = P + c * CH + (e & 1) * 5;
        const float cx = pb[0], cy = pb[1], bw = pb[2], bh = pb[3];
        boxS[e] = make_float4(cx - 0.5f * bw, cy - 0.5f * bh,
                              cx + 0.5f * bw, cy + 0.5f * bh);
    }
    for (int e = lane; e < nBox; e += 64) {
        const int c = clist[e >> 1];
        const float* tb = T + c * CH + (e & 1) * 5;
        const float* pb = P + c * CH + (e & 1) * 5;
        const float tcx = tb[0], tcy = tb[1], tw = tb[2], th = tb[3];
        const float tx1 = tcx - 0.5f * tw, ty1 = tcy - 0.5f * th;
        const float tx2 = tcx + 0.5f * tw, ty2 = tcy + 0.5f * th;
        const float ta = (tx2 - tx1) * (ty2 - ty1);
        float maxiou = 0.f;
        for (int i = 0; i < nBox; ++i) {
            const float4 b4 = boxS[i];               // wave-uniform = broadcast
            const float lx = fmaxf(b4.x, tx1), ly = fmaxf(b4.y, ty1);
            const float rx = fminf(b4.z, tx2), ry = fminf(b4.w, ty2);
            const float iw = fmaxf(rx - lx, 0.f), ih = fmaxf(ry - ly, 0.f);
            const float inter = iw * ih;
            const float pa = (b4.z - b4.x) * (b4.w - b4.y);
            const float un = pa + ta - inter;
            const float iou = inter / (un > 0.f ? un : 1.f);
            maxiou = fmaxf(maxiou, iou);
        }
        if (maxiou != 0.f) {                         // cmask
            const float dcx = pb[0] - tcx, dcy = pb[1] - tcy;
            coord += dcx * dcx + dcy * dcy;
            const float dw = sqrtf(pb[2]) - sqrtf(tw);
            const float dh = sqrtf(pb[3]) - sqrtf(th);
            coord += dw * dw + dh * dh;
            const float dc = pb[4] - tb[4];
            objc += dc * dc;
        }
    }
}

__global__ __launch_bounds__(THREADS) void yolo_main(const float* __restrict__ pred,
                                                     const float* __restrict__ targ,
                                                     float* __restrict__ ws, int B) {
    const int w = threadIdx.x >> 6;
    const int lane = threadIdx.x & 63;
    const int waveId = blockIdx.x * 2 + w;
    const int r0 = waveId * 2, r1 = r0 + 1;
    const bool ok0 = r0 < B, ok1 = r1 < B;           // wave-uniform

    __shared__ float4 boxS[2][2 * CELLS];
    __shared__ int clist[2][CELLS];
    __shared__ float sred[2][3];

    float cls = 0.f, objc = 0.f, coord = 0.f;
    unsigned long long mask0 = 0ull, mask1 = 0ull;

    const float* P0 = pred + (size_t)r0 * ROW;
    const float* T0 = targ + (size_t)r0 * ROW;
    const float* P1 = P0 + ROW;
    const float* T1 = T0 + ROW;

    if (ok0 && ok1) {
        // ---- conf loads FIRST (oldest in vmcnt queue -> ballot waits only these)
        const int cl = lane < CELLS ? lane : CELLS - 1;
        const float c0 = T0[cl * CH + 4];
        const float c1 = T1[cl * CH + 4];

        const float4* P4 = (const float4*)P0;        // 2-row region, 16B-aligned
        const float4* T4 = (const float4*)T0;

        // ---- software pipeline: DEPTH slots in flight, rotating buffers ----
        float4 pv[DEPTH], tv[DEPTH];
        #pragma unroll
        for (int i = 0; i < DEPTH; ++i) {
            const int f = lane + i * 64;
            const int fc = f < NF4 ? f : NF4 - 1;
            pv[i] = P4[fc];
            tv[i] = T4[fc];
        }

        mask0 = __ballot((lane < CELLS) && (c0 > 0.f));
        mask1 = __ballot((lane < CELLS) && (c1 > 0.f));

        #pragma unroll
        for (int i = 0; i < SLOTS; ++i) {
            // consume slot i (after issuing its replacement)
            if (i + DEPTH < SLOTS) {
                const int f = lane + (i + DEPTH) * 64;
                const int fc = f < NF4 ? f : NF4 - 1;
                // note: written AFTER reading below would be ideal; copy first
            }
            const float4 p = pv[i % DEPTH];
            const float4 t = tv[i % DEPTH];
            if (i + DEPTH < SLOTS) {
                const int f = lane + (i + DEPTH) * 64;
                const int fc = f < NF4 ? f : NF4 - 1;
                pv[i % DEPTH] = P4[fc];
                tv[i % DEPTH] = T4[fc];
            }
            const int f = lane + i * 64;
            const bool valid = f < NF4;
            const float pe[4] = {p.x, p.y, p.z, p.w};
            const float te[4] = {t.x, t.y, t.z, t.w};
            #pragma unroll
            for (int k = 0; k < 4; ++k) {
                const unsigned j2 = 4u * (unsigned)f + (unsigned)k;  // 0..2939
                const unsigned s = j2 >= (unsigned)ROW;
                const unsigned j = j2 - s * (unsigned)ROW;           // 0..1469
                const unsigned cell = j / 30u;                       // magic mul
                const unsigned ch = j - cell * 30u;
                const unsigned long long m = s ? mask1 : mask0;
                const float wobj = (float)((m >> cell) & 1ull);
                const float d = pe[k] - te[k];
                const float d2 = d * d;
                cls += (valid && ch >= 10u) ? wobj * d2 : 0.f;
                const float nn = (ch == 4u || ch == 9u) ? d2 : 0.f;
                objc += valid ? 0.5f * (1.f - wobj) * nn : 0.f;      // NOOBJ folded
            }
        }

        boxRow(P0, T0, mask0, lane, boxS[w], clist[w], objc, coord);
        boxRow(P1, T1, mask1, lane, boxS[w], clist[w], objc, coord);
    } else if (ok0) {
        // odd-B tail: single row, simple float2 path (unused at B=8192)
        const int cl = lane < CELLS ? lane : CELLS - 1;
        mask0 = __ballot((lane < CELLS) && (T0[cl * CH + 4] > 0.f));
        const float2* P2 = (const float2*)P0;
        const float2* T2 = (const float2*)T0;
        for (int j = lane; j < ROW / 2; j += 64) {
            const float2 p = P2[j];
            const float2 t = T2[j];
            const unsigned cell = (unsigned)j / 15u;
            const unsigned ch0 = 2u * ((unsigned)j - cell * 15u);
            const float wobj = (float)((mask0 >> cell) & 1ull);
            const float dx = p.x - t.x, dy = p.y - t.y;
            cls += (ch0 >= 10u) ? wobj * (dx * dx + dy * dy) : 0.f;
            const float nn = (ch0 == 4u ? dx * dx : 0.f) + (ch0 == 8u ? dy * dy : 0.f);
            objc += 0.5f * (1.f - wobj) * nn;
        }
        boxRow(P0, T0, mask0, lane, boxS[w], clist[w], objc, coord);
    }

    // ---- wave reduce -> block triple (deterministic) ----
    cls = waveReduce(cls); objc = waveReduce(objc); coord = waveReduce(coord);
    if (lane == 0) { sred[w][0] = cls; sred[w][1] = objc; sred[w][2] = coord; }
    __syncthreads();
    if (threadIdx.x == 0) {
        const int NBLK = gridDim.x;
        ws[blockIdx.x]            = sred[0][0] + sred[1][0];
        ws[NBLK + blockIdx.x]     = sred[0][1] + sred[1][1];
        ws[2 * NBLK + blockIdx.x] = sred[0][2] + sred[1][2];
    }
}

__global__ __launch_bounds__(1024) void yolo_reduce(const float* __restrict__ ws,
                                                    float* __restrict__ out,
                                                    int NBLK, float invB) {
    const int tid = threadIdx.x;
    const int w = tid >> 6, lane = tid & 63;
    float c = 0.f, o = 0.f, x = 0.f;
    for (int i = tid; i < NBLK; i += 1024) {
        c += ws[i];
        o += ws[NBLK + i];
        x += ws[2 * NBLK + i];
    }
    c = waveReduce(c); o = waveReduce(o); x = waveReduce(x);
    __shared__ float sred[16][3];
    if (lane == 0) { sred[w][0] = c; sred[w][1] = o; sred[w][2] = x; }
    __syncthreads();
    if (tid == 0) {
        float C = 0.f, O = 0.f, X = 0.f;
        #pragma unroll
        for (int k = 0; k < 16; ++k) { C += sred[k][0]; O += sred[k][1]; X += sred[k][2]; }
        const float bcls = C * invB;
        const float bobj = O * invB;                 // noobj*0.5 folded upstream
        const float bcoord = X * 5.0f * invB;        // COORD_LAMBDA
        out[0] = bcls + bobj + bcoord;
        out[1] = bcls;
        out[2] = bobj;
        out[3] = bcoord;
    }
}

extern "C" void kernel_launch(void* const* d_in, const int* in_sizes, int n_in,
                              void* d_out, int out_size, void* d_ws, size_t ws_size,
                              hipStream_t stream) {
    const float* pred = (const float*)d_in[0];
    const float* targ = (const float*)d_in[1];
    float* ws = (float*)d_ws;
    float* out = (float*)d_out;
    const int B = in_sizes[0] / ROW;
    const int NBLK = (B + 3) / 4;                    // 4 rows per block

    yolo_main<<<NBLK, THREADS, 0, stream>>>(pred, targ, ws, B);
    yolo_reduce<<<1, 1024, 0, stream>>>(ws, out, NBLK, 1.0f / (float)B);
}

// Round 11
// 130.234 us; speedup vs baseline: 2.4814x; 1.0401x over previous
//
#include <hip/hip_runtime.h>

#define CH 30
#define CELLS 49
#define ROW 1470            // floats per batch row
#define NPAIR 735           // float2 pairs per row
#define BATCH 6             // pairs per load batch (12 loads in flight)
#define THREADS 256         // 4 waves per block, 1 row per wave

__device__ __forceinline__ float waveReduce(float v) {
    #pragma unroll
    for (int o = 32; o > 0; o >>= 1) v += __shfl_xor(v, o, 64);
    return v;
}

// nontemporal 8B load (nt flag: bypass L1, stay in L2/L3)
__device__ __forceinline__ float2 ntload2(const float* p) {
    typedef float v2f __attribute__((ext_vector_type(2)));
    const v2f v = __builtin_nontemporal_load((const v2f*)p);
    return make_float2(v.x, v.y);
}

// Per-wave box/IoU losses for one row. boxS/clist are wave-private LDS
// slices; wave lockstep + compiler lgkmcnt ordering -> no barriers needed.
__device__ __forceinline__ void boxRow(const float* __restrict__ P,
                                       const float* __restrict__ T,
                                       unsigned long long mask, int lane,
                                       float4* boxS, int* clist,
                                       float& objc, float& coord) {
    const int nObj = __popcll(mask);
    const bool isObj = (lane < CELLS) && ((mask >> lane) & 1ull);
    if (isObj) clist[__popcll(mask & ((1ull << lane) - 1ull))] = lane;
    const int nBox = 2 * nObj;

    for (int e = lane; e < nBox; e += 64) {
        const int c = clist[e >> 1];
        const float* pb = P + c * CH + (e & 1) * 5;
        const float cx = pb[0], cy = pb[1], bw = pb[2], bh = pb[3];
        boxS[e] = make_float4(cx - 0.5f * bw, cy - 0.5f * bh,
                              cx + 0.5f * bw, cy + 0.5f * bh);
    }
    for (int e = lane; e < nBox; e += 64) {
        const int c = clist[e >> 1];
        const float* tb = T + c * CH + (e & 1) * 5;
        const float* pb = P + c * CH + (e & 1) * 5;
        const float tcx = tb[0], tcy = tb[1], tw = tb[2], th = tb[3];
        const float tx1 = tcx - 0.5f * tw, ty1 = tcy - 0.5f * th;
        const float tx2 = tcx + 0.5f * tw, ty2 = tcy + 0.5f * th;
        const float ta = (tx2 - tx1) * (ty2 - ty1);
        float maxiou = 0.f;
        for (int i = 0; i < nBox; ++i) {
            const float4 b4 = boxS[i];               // wave-uniform = broadcast
            const float lx = fmaxf(b4.x, tx1), ly = fmaxf(b4.y, ty1);
            const float rx = fminf(b4.z, tx2), ry = fminf(b4.w, ty2);
            const float iw = fmaxf(rx - lx, 0.f), ih = fmaxf(ry - ly, 0.f);
            const float inter = iw * ih;
            const float pa = (b4.z - b4.x) * (b4.w - b4.y);
            const float un = pa + ta - inter;
            const float iou = inter / (un > 0.f ? un : 1.f);
            maxiou = fmaxf(maxiou, iou);
        }
        if (maxiou != 0.f) {                         // cmask
            const float dcx = pb[0] - tcx, dcy = pb[1] - tcy;
            coord += dcx * dcx + dcy * dcy;
            const float dw = sqrtf(pb[2]) - sqrtf(tw);
            const float dh = sqrtf(pb[3]) - sqrtf(th);
            coord += dw * dw + dh * dh;
            const float dc = pb[4] - tb[4];
            objc += dc * dc;
        }
    }
}

__device__ __forceinline__ void consumePair(int j, float2 p, float2 t,
                                            unsigned long long mask,
                                            float& cls, float& objc) {
    const bool valid = j < NPAIR;
    const int cell = (j * 17477) >> 18;              // j/15 for j<=767
    const int ch0 = 2 * (j - cell * 15);             // even channel of the pair
    const float wobj = (float)((mask >> cell) & 1ull);
    const float dx = p.x - t.x;
    const float dy = p.y - t.y;
    // class loss: channels 10..29, obj cells only
    cls += (valid && ch0 >= 10) ? wobj * (dx * dx + dy * dy) : 0.f;
    // noobj conf loss x0.5 folded: ch4 (.x of pair rem2), ch9 (.y of pair rem4)
    const float nn = (ch0 == 4 ? dx * dx : 0.f) + (ch0 == 8 ? dy * dy : 0.f);
    objc += valid ? 0.5f * (1.f - wobj) * nn : 0.f;
}

__global__ __launch_bounds__(THREADS, 7) void yolo_main(const float* __restrict__ pred,
                                                        const float* __restrict__ targ,
                                                        float* __restrict__ ws, int B) {
    const int w = threadIdx.x >> 6;
    const int lane = threadIdx.x & 63;
    const int r = blockIdx.x * 4 + w;
    const bool rowOk = (r < B);                      // wave-uniform

    __shared__ float4 boxS[4][2 * CELLS];            // 6272 B
    __shared__ int clist[4][CELLS];                  // 784 B

    float cls = 0.f, objc = 0.f, coord = 0.f;

    if (rowOk) {
        const float* P = pred + (size_t)r * ROW;
        const float* T = targ + (size_t)r * ROW;

        // conf gather FIRST (oldest in vmcnt queue; overlaps batch-1 stream)
        const int cl = lane < CELLS ? lane : CELLS - 1;
        const float conf = T[cl * CH + 4];

        // batch 1: issue 12 NT loads
        float2 pv[BATCH], tv[BATCH];
        #pragma unroll
        for (int i = 0; i < BATCH; ++i) {
            const int j = lane + i * 64;             // < 384, always valid
            pv[i] = ntload2(P + 2 * j);
            tv[i] = ntload2(T + 2 * j);
        }

        // ballot waits only the conf load (compiler emits vmcnt(12))
        const unsigned long long mask = __ballot((lane < CELLS) && (conf > 0.f));

        // consume batch 1
        #pragma unroll
        for (int i = 0; i < BATCH; ++i)
            consumePair(lane + i * 64, pv[i], tv[i], mask, cls, objc);

        // batch 2: issue 12 NT loads (clamped tail), consume
        #pragma unroll
        for (int i = 0; i < BATCH; ++i) {
            const int j = lane + (BATCH + i) * 64;
            const int jc = j < NPAIR ? j : NPAIR - 1;
            pv[i] = ntload2(P + 2 * jc);
            tv[i] = ntload2(T + 2 * jc);
        }
        #pragma unroll
        for (int i = 0; i < BATCH; ++i)
            consumePair(lane + (BATCH + i) * 64, pv[i], tv[i], mask, cls, objc);

        // box/IoU losses (gathers hit L2/L3-warm lines)
        boxRow(P, T, mask, lane, boxS[w], clist[w], objc, coord);
    }

    // wave reduce -> per-row triple; NO barriers anywhere in this kernel
    cls = waveReduce(cls); objc = waveReduce(objc); coord = waveReduce(coord);
    if (rowOk && lane == 0) {
        ws[r] = cls;
        ws[B + r] = objc;
        ws[2 * B + r] = coord;
    }
}

__global__ __launch_bounds__(1024) void yolo_reduce(const float* __restrict__ ws,
                                                    float* __restrict__ out,
                                                    int B, float invB) {
    const int tid = threadIdx.x;
    const int w = tid >> 6, lane = tid & 63;
    float c = 0.f, o = 0.f, x = 0.f;
    for (int i = tid; i < B; i += 1024) {
        c += ws[i];
        o += ws[B + i];
        x += ws[2 * B + i];
    }
    c = waveReduce(c); o = waveReduce(o); x = waveReduce(x);
    __shared__ float sred[16][3];
    if (lane == 0) { sred[w][0] = c; sred[w][1] = o; sred[w][2] = x; }
    __syncthreads();
    if (tid == 0) {
        float C = 0.f, O = 0.f, X = 0.f;
        #pragma unroll
        for (int k = 0; k < 16; ++k) { C += sred[k][0]; O += sred[k][1]; X += sred[k][2]; }
        const float bcls = C * invB;
        const float bobj = O * invB;                 // noobj*0.5 folded upstream
        const float bcoord = X * 5.0f * invB;        // COORD_LAMBDA
        out[0] = bcls + bobj + bcoord;
        out[1] = bcls;
        out[2] = bobj;
        out[3] = bcoord;
    }
}

extern "C" void kernel_launch(void* const* d_in, const int* in_sizes, int n_in,
                              void* d_out, int out_size, void* d_ws, size_t ws_size,
                              hipStream_t stream) {
    const float* pred = (const float*)d_in[0];
    const float* targ = (const float*)d_in[1];
    float* ws = (float*)d_ws;
    float* out = (float*)d_out;
    const int B = in_sizes[0] / ROW;
    const int NBLK = (B + 3) / 4;                    // 4 rows per block

    yolo_main<<<NBLK, THREADS, 0, stream>>>(pred, targ, ws, B);
    yolo_reduce<<<1, 1024, 0, stream>>>(ws, out, B, 1.0f / (float)B);
}